// Round 11
// baseline (248.587 us; speedup 1.0000x reference)
//
#include <hip/hip_runtime.h>
#include <hip/hip_bf16.h>
#include <stdint.h>

// Problem constants
#define BATCH 64
#define CH 3
#define HW 224
#define PP 7
#define GHW 32           // 32x32 patches
#define PD 147           // 7*7*3
#define DIM 1024
#define NTOK 65536       // 64 * 1024 tokens

typedef int   i32x4 __attribute__((ext_vector_type(4)));
typedef float f32x4v __attribute__((ext_vector_type(4)));
typedef float f32x2v __attribute__((ext_vector_type(2)));

// ---------------- prelude 1: mean|W| partials + pe table, one launch ----------------
__global__ void prep1(const float* __restrict__ W, float* __restrict__ part,
                      float* __restrict__ pe2) {
    int tid = threadIdx.x;
    if (blockIdx.x < 147) {
        __shared__ float red[256];
        int base = blockIdx.x * 1024;             // 147 blocks * 1024 = 150528
        float s = fabsf(W[base + tid]) + fabsf(W[base + tid + 256]) +
                  fabsf(W[base + tid + 512]) + fabsf(W[base + tid + 768]);
        red[tid] = s;
        __syncthreads();
        for (int off = 128; off > 0; off >>= 1) {
            if (tid < off) red[tid] += red[tid + off];
            __syncthreads();
        }
        if (tid == 0) part[blockIdx.x] = red[0];
    } else {
        int id = (blockIdx.x - 147) * 256 + tid;  // < 16384 = 32*512
        int g = id >> 9, c = id & 511;
        int k = c & 255;
        float omega = exp2f(-13.287712379549449f * (float)k * (1.0f / 255.0f));
        float arg = (float)g * omega;
        pe2[id] = (c < 256) ? sinf(arg) : cosf(arg);
    }
}

// ---------------- ternary weight quant -> int8, MFMA fragment layout ----------------
// Wq layout: [c = k>>4 (12)][d(1024)][j = k&15] int8, k padded to 192. 192 KB total.
__global__ void wquant(const float* __restrict__ W, const float* __restrict__ part,
                       float* __restrict__ swbuf, signed char* __restrict__ Wq) {
    __shared__ float red[256];
    int tid = threadIdx.x;
    red[tid] = (tid < 147) ? part[tid] : 0.f;
    __syncthreads();
    for (int off = 128; off > 0; off >>= 1) {
        if (tid < off) red[tid] += red[tid + off];
        __syncthreads();
    }
    float m = fmaxf(red[0] * (1.0f / 150528.0f), 1e-5f);
    float sw = 1.0f / m;
    if (blockIdx.x == 0 && tid == 0) swbuf[0] = m;   // dequant scale for gemm

    int e = blockIdx.x * 256 + tid;               // < 196608 = 1024*192
    int d = e / 192, k = e % 192;
    float t = 0.f;
    if (k < 147) {
        t = rintf(W[d * 147 + k] * sw);
        t = fminf(fmaxf(t, -1.f), 1.f);
    }
    Wq[(((k >> 4) << 10) | d) * 16 + (k & 15)] = (signed char)(int)t;
}

// ---------------- fused patchify + LN1 + int8 quant + i8 GEMM + LN2 + posemb ----------
// r11: PERSISTENT blocks. grid = 512 blocks x 8 tiles (balanced: 64 blocks/XCD,
// 512 tiles/XCD). Tile = 16 tokens x 1024 cols, 512 threads = 8 waves (wn 0..7),
// wave tile 16 tokens x 128 cols, acc = 8 i32x4. Operand-swapped MFMA
// (lane&15 = token, lg*4+rr = 4 consecutive cols). Wave-private LDS-transpose
// epilogue -> 4 rows x 256 B contiguous nt stores.
// Pipeline: next tile's x-loads are issued BEFORE this tile's stores (FIFO vmcnt ->
// phase-0 ds_write waits vmcnt(8), not full drain); the 8 nt stores of tile t stay
// in flight across the whole compute of tile t+1 -> store pipe fed continuously,
// breaking the phase convoy that capped write BW at ~2.7 TB/s through r10.
// LDS (34816 B, T aliases the phase buffers):
//   phase 0-2 : xs [0,9408) f32 ; A8 [9408,12736) ; stats [12736,13760) ; sxl [13760,13824)
//   epilogue  : T  [0,34816) = 8 wave-private regions of 272 16B-units (16x17 stride)
__global__ __launch_bounds__(512, 4) void fused(
    const float* __restrict__ x, const float* __restrict__ g1,
    const float* __restrict__ b1, const signed char* __restrict__ Wq,
    const float* __restrict__ swbuf, const float* __restrict__ bproj,
    const float* __restrict__ g2, const float* __restrict__ b2,
    const float* __restrict__ pe2, float* __restrict__ out) {
    extern __shared__ char lds[];
    float*        xs    = (float*)lds;
    uint32_t*     A8w   = (uint32_t*)(lds + 9408);
    const i32x4*  A4    = (const i32x4*)(lds + 9408);
    f32x2v*       stats = (f32x2v*)(lds + 12736); // [wn(8)][token(16)] {sum,sq}
    float*        sxl   = (float*)(lds + 13760);
    f32x4v*       T     = (f32x4v*)lds;           // epilogue transpose buffer (aliases)

    int tid = threadIdx.x;
    int wave = tid >> 6, lane = tid & 63;
    int wn = wave;                                // col slice [wn*128, wn*128+128)
    int l15 = lane & 15, lg = lane >> 4;

    int xcd = blockIdx.x & 7, local = blockIdx.x >> 3;   // 64 blocks per XCD
    int tbase = xcd * 512 + local;                // tiles: tbase + i*64, i=0..7

    const f32x4v* x4  = (const f32x4v*)x;
    const i32x4*  Wq4 = (const i32x4*)Wq;
    f32x4v*       xs4 = (f32x4v*)xs;
    float inv_sw = swbuf[0];
    int bcol = wn * 128 + l15;

    // ---- prefetch x for tile 0 ----
    f32x4v xv[2];
    {
        int lt = tbase;
        int gh = lt >> 7, b = (lt >> 1) & 63, half = lt & 1;
        int base4 = b * 37632 + gh * 392 + half * 28;
#pragma unroll
        for (int it = 0; it < 2; it++) {
            int j = tid + it * 512;
            if (j < 588) {
                int c = j / 196, rem2 = j - c * 196;
                int p1 = rem2 / 28, i4 = rem2 - p1 * 28;
                xv[it] = x4[base4 + c * 12544 + p1 * 56 + i4];
            }
        }
    }

#pragma unroll 1
    for (int i = 0; i < 8; i++) {
        int lt = tbase + i * 64;
        int gh = lt >> 7, b = (lt >> 1) & 63, half = lt & 1;
        int rowbase = b * 1024 + gh * 32 + half * 16;

        if (i) __syncthreads();                   // BAR E: prev tile's T reads done

        // ---- phase 0: ds_write prefetched x (waits vmcnt for loads, not stores) ----
#pragma unroll
        for (int it = 0; it < 2; it++) {
            int j = tid + it * 512;
            if (j < 588) xs4[j] = xv[it];
        }
        __syncthreads();                          // BAR A

        // ---- phase 1: LN1 + per-token absmax int8 fake-quant -> A8 (256 threads) ----
        if (tid < 256) {
            int r = tid >> 4, sub = tid & 15;     // token r (0..15), k = sub*12 + ii
            float vals[12];
            float sum = 0.f, sq = 0.f;
#pragma unroll
            for (int ii = 0; ii < 12; ii++) {
                int k = sub * 12 + ii;
                float val = 0.f;
                if (k < 147) {
                    int c = k % 3, pp = k / 3, p1 = pp / 7, p2 = pp % 7;
                    val = xs[c * 784 + p1 * 112 + r * 7 + p2];
                }
                vals[ii] = val;
                sum += val; sq += val * val;
            }
#pragma unroll
            for (int m = 1; m < 16; m <<= 1) {
                sum += __shfl_xor(sum, m);
                sq  += __shfl_xor(sq, m);
            }
            float mu = sum * (1.0f / 147.0f);
            float rstd1 = rsqrtf(sq * (1.0f / 147.0f) - mu * mu + 1e-5f);
            float amax = 0.f;
#pragma unroll
            for (int ii = 0; ii < 12; ii++) {
                int k = sub * 12 + ii;
                if (k < 147) {
                    float v = (vals[ii] - mu) * rstd1 * g1[k] + b1[k];
                    vals[ii] = v;
                    amax = fmaxf(amax, fabsf(v));
                }
            }
#pragma unroll
            for (int m = 1; m < 16; m <<= 1) amax = fmaxf(amax, __shfl_xor(amax, m));
            float mx = fmaxf(amax, 1e-5f);
            float sx = 127.0f / mx;
            uint32_t w0 = 0, w1 = 0, w2 = 0;
#pragma unroll
            for (int ii = 0; ii < 12; ii++) {
                int k = sub * 12 + ii;
                float qv = 0.f;
                if (k < 147) qv = fminf(fmaxf(rintf(vals[ii] * sx), -128.f), 127.f);
                uint32_t byte = (uint32_t)((int)qv & 0xFF);
                if (ii < 4)      w0 |= byte << (8 * ii);
                else if (ii < 8) w1 |= byte << (8 * (ii - 4));
                else             w2 |= byte << (8 * (ii - 8));
            }
            int wb = r * 52 + sub * 3;            // (r*208 + sub*12)/4
            A8w[wb] = w0; A8w[wb + 1] = w1; A8w[wb + 2] = w2;
            if (sub == 0) sxl[r] = mx * (1.0f / 127.0f);
        }
        __syncthreads();                          // BAR B

        // ---- phase 2: i8 GEMM (operand-swapped), B direct from L2 ----
        i32x4 acc[8];
#pragma unroll
        for (int n = 0; n < 8; n++) acc[n] = (i32x4)0;

#pragma unroll 1
        for (int kk = 0; kk < 3; kk++) {
            i32x4 a = A4[l15 * 13 + kk * 4 + lg]; // token = l15, k-chunk = lg
            i32x4 bf[8];
#pragma unroll
            for (int n = 0; n < 8; n++)
                bf[n] = Wq4[(kk * 4 + lg) * 1024 + bcol + n * 16];
#pragma unroll
            for (int n = 0; n < 8; n++)           // D[dcol][token]: operands swapped
                acc[n] = __builtin_amdgcn_mfma_i32_16x16x64_i8(bf[n], a, acc[n], 0, 0, 0);
        }

        // ---- phase 3a: dequant + bias, LN2 stats over 1024 cols ----
        int token = l15;
        float sc = sxl[token] * inv_sw;
        int colbase = wn * 128 + lg * 4;

        float s = 0.f, q = 0.f;
#pragma unroll
        for (int n = 0; n < 8; n++) {
            int col = colbase + n * 16;
            f32x4v bp = *(const f32x4v*)(bproj + col);
#pragma unroll
            for (int rr = 0; rr < 4; rr++) {
                float v = (float)acc[n][rr] * sc + bp[rr];
                acc[n][rr] = __float_as_int(v);   // bit-cast in place
                s += v; q += v * v;
            }
        }
        s += __shfl_xor(s, 16); s += __shfl_xor(s, 32);
        q += __shfl_xor(q, 16); q += __shfl_xor(q, 32);
        if (lg == 0) {
            f32x2v sv; sv[0] = s; sv[1] = q;
            stats[wn * 16 + token] = sv;          // [wn][token], b64, conflict-free
        }
        __syncthreads();                          // BAR C

        float st = 0.f, qt = 0.f;
#pragma unroll
        for (int w = 0; w < 8; w++) {
            f32x2v sv = stats[w * 16 + token];
            st += sv[0]; qt += sv[1];
        }
        float mean = st * (1.0f / 1024.0f);
        float rstd = rsqrtf(qt * (1.0f / 1024.0f) - mean * mean + 1e-5f);
        __syncthreads();                          // BAR D: xs/A8/stats/sxl now dead

        // ---- prefetch x for tile i+1 (ISSUED BEFORE the stores; FIFO retire) ----
        if (i < 7) {
            int ltn = tbase + (i + 1) * 64;
            int ghn = ltn >> 7, bn = (ltn >> 1) & 63, hn = ltn & 1;
            int base4 = bn * 37632 + ghn * 392 + hn * 28;
#pragma unroll
            for (int it = 0; it < 2; it++) {
                int j = tid + it * 512;
                if (j < 588) {
                    int c = j / 196, rem2 = j - c * 196;
                    int p1 = rem2 / 28, i4 = rem2 - p1 * 28;
                    xv[it] = x4[base4 + c * 12544 + p1 * 56 + i4];
                }
            }
        }

        // ---- phase 3b: LN2 apply + posemb, LDS transpose, full-line nt stores ----
        const float* perow = (wn < 4) ? (pe2 + (half * 16 + token) * 512)
                                      : (pe2 + gh * 512 - 512);
        int wbaseu = wave * 272;                  // 272 16B-units per wave region

#pragma unroll
        for (int p = 0; p < 2; p++) {
#pragma unroll
            for (int ni = 0; ni < 4; ni++) {
                int n = p * 4 + ni;
                int col = colbase + n * 16;
                f32x4v gg = *(const f32x4v*)(g2 + col);
                f32x4v bb = *(const f32x4v*)(b2 + col);
                f32x4v pv = *(const f32x4v*)(perow + col);
                f32x4v o;
#pragma unroll
                for (int rr = 0; rr < 4; rr++) {
                    float v = __int_as_float(acc[n][rr]);
                    o[rr] = (v - mean) * rstd * gg[rr] + bb[rr] + pv[rr];
                }
                T[wbaseu + l15 * 17 + ni * 4 + lg] = o;
            }
#pragma unroll
            for (int j = 0; j < 4; j++) {
                f32x4v v = T[wbaseu + (j * 4 + lg) * 17 + l15];
                int row = rowbase + j * 4 + lg;
                int col = wn * 128 + p * 64 + l15 * 4;
                __builtin_nontemporal_store(v, (f32x4v*)(out + (size_t)row * 1024 + col));
            }
        }
    }
}

extern "C" void kernel_launch(void* const* d_in, const int* in_sizes, int n_in,
                              void* d_out, int out_size, void* d_ws, size_t ws_size,
                              hipStream_t stream) {
    const float* x     = (const float*)d_in[0];
    const float* ln1_g = (const float*)d_in[1];
    const float* ln1_b = (const float*)d_in[2];
    const float* W     = (const float*)d_in[3];
    const float* bproj = (const float*)d_in[4];
    const float* ln2_g = (const float*)d_in[5];
    const float* ln2_b = (const float*)d_in[6];
    float* out = (float*)d_out;

    // workspace layout
    char* ws = (char*)d_ws;
    float*       pe2   = (float*)ws;                           // 65,536 B
    signed char* Wq    = (signed char*)(ws + 65536u);          // 196,608 B
    float*       part  = (float*)(ws + 65536u + 196608u);      // 147 floats
    float*       swbuf = part + 160;

    prep1<<<211, 256, 0, stream>>>(W, part, pe2);
    wquant<<<768, 256, 0, stream>>>(W, part, swbuf, Wq);
    fused<<<512, 512, 34816, stream>>>(x, ln1_g, ln1_b, Wq, swbuf, bproj,
                                       ln2_g, ln2_b, pe2, out);
}

// Round 12
// 111.771 us; speedup vs baseline: 2.2241x; 2.2241x over previous
//
#include <hip/hip_runtime.h>
#include <hip/hip_bf16.h>
#include <stdint.h>

// Problem constants
#define BATCH 64
#define CH 3
#define HW 224
#define PP 7
#define GHW 32           // 32x32 patches
#define PD 147           // 7*7*3
#define DIM 1024
#define NTOK 65536       // 64 * 1024 tokens

typedef int   i32x4 __attribute__((ext_vector_type(4)));
typedef float f32x4v __attribute__((ext_vector_type(4)));
typedef float f32x2v __attribute__((ext_vector_type(2)));

// ---------------- prelude 1: mean|W| partials + pe table, one launch ----------------
__global__ void prep1(const float* __restrict__ W, float* __restrict__ part,
                      float* __restrict__ pe2) {
    int tid = threadIdx.x;
    if (blockIdx.x < 147) {
        __shared__ float red[256];
        int base = blockIdx.x * 1024;             // 147 blocks * 1024 = 150528
        float s = fabsf(W[base + tid]) + fabsf(W[base + tid + 256]) +
                  fabsf(W[base + tid + 512]) + fabsf(W[base + tid + 768]);
        red[tid] = s;
        __syncthreads();
        for (int off = 128; off > 0; off >>= 1) {
            if (tid < off) red[tid] += red[tid + off];
            __syncthreads();
        }
        if (tid == 0) part[blockIdx.x] = red[0];
    } else {
        int id = (blockIdx.x - 147) * 256 + tid;  // < 16384 = 32*512
        int g = id >> 9, c = id & 511;
        int k = c & 255;
        float omega = exp2f(-13.287712379549449f * (float)k * (1.0f / 255.0f));
        float arg = (float)g * omega;
        pe2[id] = (c < 256) ? sinf(arg) : cosf(arg);
    }
}

// ---------------- ternary weight quant -> int8, MFMA fragment layout ----------------
// Wq layout: [c = k>>4 (12)][d(1024)][j = k&15] int8, k padded to 192. 192 KB total.
__global__ void wquant(const float* __restrict__ W, const float* __restrict__ part,
                       float* __restrict__ swbuf, signed char* __restrict__ Wq) {
    __shared__ float red[256];
    int tid = threadIdx.x;
    red[tid] = (tid < 147) ? part[tid] : 0.f;
    __syncthreads();
    for (int off = 128; off > 0; off >>= 1) {
        if (tid < off) red[tid] += red[tid + off];
        __syncthreads();
    }
    float m = fmaxf(red[0] * (1.0f / 150528.0f), 1e-5f);
    float sw = 1.0f / m;
    if (blockIdx.x == 0 && tid == 0) swbuf[0] = m;   // dequant scale for gemm

    int e = blockIdx.x * 256 + tid;               // < 196608 = 1024*192
    int d = e / 192, k = e % 192;
    float t = 0.f;
    if (k < 147) {
        t = rintf(W[d * 147 + k] * sw);
        t = fminf(fmaxf(t, -1.f), 1.f);
    }
    Wq[(((k >> 4) << 10) | d) * 16 + (k & 15)] = (signed char)(int)t;
}

// ---------------- fused patchify + LN1 + int8 quant + i8 GEMM + LN2 + posemb ----------
// r12: 256-thread blocks (4 waves), tile = 16 tokens x 1024 cols, wave tile 16x256
// (acc = 16 i32x4 = 64 AGPR; live ~95 < 128 budget at bounds(256,4) -> NO spill,
// unlike r10's bounds(512,6) squeeze to 85). Grid 4096, XCD-swizzled gh-major.
// 4 independent blocks/CU at staggered phases -> 4 store bursts in flight (vs 2 in
// r8), attacking the phase-convoy that capped effective write BW at ~2.7 TB/s.
// Operand-swapped MFMA (lane&15 = token, lg*4+rr = 4 consecutive cols); wave-private
// LDS-transpose epilogue -> 4 rows x 256 B contiguous nt stores. 3 barriers
// (stats region NOT aliased by T, so r8's BAR D is gone).
// LDS (30720 B):
//   xs   [0,     9408)  : x-stage [c(3)][p1(7)][112] f32   (dead after phase 1)
//   A8   [9408, 12736)  : quantized A int8 [row(16)][208]   (dead after GEMM)
//   stats[12736, 13248) : [wn(4)][token(16)] {sum,sq} f32   (never aliased)
//   sxl  [13248, 13312) : per-token dequant scale f32       (never aliased)
//   T    [13312, 30720) : 4 wave-private regions of 272 16B-units (16x17 stride),
//                         aliases xs/A8 only.
__global__ __launch_bounds__(256, 4) void fused(
    const float* __restrict__ x, const float* __restrict__ g1,
    const float* __restrict__ b1, const signed char* __restrict__ Wq,
    const float* __restrict__ swbuf, const float* __restrict__ bproj,
    const float* __restrict__ g2, const float* __restrict__ b2,
    const float* __restrict__ pe2, float* __restrict__ out) {
    extern __shared__ char lds[];
    float*        xs    = (float*)lds;
    uint32_t*     A8w   = (uint32_t*)(lds + 9408);
    const i32x4*  A4    = (const i32x4*)(lds + 9408);
    f32x2v*       stats = (f32x2v*)(lds + 12736); // [wn(4)][token(16)] {sum,sq}
    float*        sxl   = (float*)(lds + 13248);
    f32x4v*       T     = (f32x4v*)(lds + 13312); // epilogue transpose buffer

    int tid = threadIdx.x;
    int wave = tid >> 6, lane = tid & 63;
    int wn = wave;                                // col slice [wn*256, wn*256+256)
    int l15 = lane & 15, lg = lane >> 4;

    // XCD-swizzled, gh-major: XCD x owns lblk [x*512, x*512+512) -> gh in [x*4, x*4+4)
    int lblk = (blockIdx.x & 7) * 512 + (blockIdx.x >> 3);
    int gh = lblk >> 7;
    int rem = lblk & 127;
    int b = rem >> 1, half = rem & 1;
    int rowbase = b * 1024 + gh * 32 + half * 16; // output token base

    // ---- phase 0: coalesced x stage (3 ch x 7 rows x 112 floats, as float4) ----
    const f32x4v* x4 = (const f32x4v*)x;
    int base4 = b * 37632 + gh * 392 + half * 28;
    f32x4v* xs4 = (f32x4v*)xs;
#pragma unroll
    for (int it = 0; it < 3; it++) {
        int j = tid + it * 256;
        if (j < 588) {
            int c = j / 196, rem2 = j - c * 196;
            int p1 = rem2 / 28, i4 = rem2 - p1 * 28;
            xs4[j] = x4[base4 + c * 12544 + p1 * 56 + i4];
        }
    }
    __syncthreads();                              // BAR A

    // ---- phase 1: LN1 + per-token absmax int8 fake-quant -> A8 (all 256 threads) ----
    {
        int r = tid >> 4, sub = tid & 15;         // token r (0..15), k = sub*12 + i
        float vals[12];
        float sum = 0.f, sq = 0.f;
#pragma unroll
        for (int i = 0; i < 12; i++) {
            int k = sub * 12 + i;
            float val = 0.f;
            if (k < 147) {
                int c = k % 3, pp = k / 3, p1 = pp / 7, p2 = pp % 7;
                val = xs[c * 784 + p1 * 112 + r * 7 + p2];
            }
            vals[i] = val;
            sum += val; sq += val * val;
        }
#pragma unroll
        for (int m = 1; m < 16; m <<= 1) {
            sum += __shfl_xor(sum, m);
            sq  += __shfl_xor(sq, m);
        }
        float mu = sum * (1.0f / 147.0f);
        float rstd1 = rsqrtf(sq * (1.0f / 147.0f) - mu * mu + 1e-5f);
        float amax = 0.f;
#pragma unroll
        for (int i = 0; i < 12; i++) {
            int k = sub * 12 + i;
            if (k < 147) {
                float v = (vals[i] - mu) * rstd1 * g1[k] + b1[k];
                vals[i] = v;
                amax = fmaxf(amax, fabsf(v));
            }
        }
#pragma unroll
        for (int m = 1; m < 16; m <<= 1) amax = fmaxf(amax, __shfl_xor(amax, m));
        float mx = fmaxf(amax, 1e-5f);
        float sx = 127.0f / mx;
        uint32_t w0 = 0, w1 = 0, w2 = 0;
#pragma unroll
        for (int i = 0; i < 12; i++) {
            int k = sub * 12 + i;
            float qv = 0.f;
            if (k < 147) qv = fminf(fmaxf(rintf(vals[i] * sx), -128.f), 127.f);
            uint32_t byte = (uint32_t)((int)qv & 0xFF);
            if (i < 4)      w0 |= byte << (8 * i);
            else if (i < 8) w1 |= byte << (8 * (i - 4));
            else            w2 |= byte << (8 * (i - 8));
        }
        int wb = r * 52 + sub * 3;                // (r*208 + sub*12)/4
        A8w[wb] = w0; A8w[wb + 1] = w1; A8w[wb + 2] = w2;
        if (sub == 0) sxl[r] = mx * (1.0f / 127.0f);
    }
    __syncthreads();                              // BAR B

    // ---- phase 2: i8 GEMM (operand-swapped), B direct from L2, rolled kk loop ----
    i32x4 acc[16];
#pragma unroll
    for (int n = 0; n < 16; n++) acc[n] = (i32x4)0;

    const i32x4* Wq4 = (const i32x4*)Wq;
    int bcol = wn * 256 + l15;

#pragma unroll 1
    for (int kk = 0; kk < 3; kk++) {
        i32x4 a = A4[l15 * 13 + kk * 4 + lg];     // token = l15, k-chunk = lg
#pragma unroll
        for (int n = 0; n < 16; n++) {
            i32x4 bf = Wq4[(kk * 4 + lg) * 1024 + bcol + n * 16];
            acc[n] = __builtin_amdgcn_mfma_i32_16x16x64_i8(bf, a, acc[n], 0, 0, 0);
        }
    }

    // ---- phase 3a: dequant + bias, LN2 stats over 1024 cols ----
    float inv_sw = swbuf[0];
    int token = l15;
    float sc = sxl[token] * inv_sw;
    int colbase = wn * 256 + lg * 4;

    float s = 0.f, q = 0.f;
#pragma unroll
    for (int n = 0; n < 16; n++) {
        int col = colbase + n * 16;
        f32x4v bp = *(const f32x4v*)(bproj + col);
#pragma unroll
        for (int rr = 0; rr < 4; rr++) {
            float v = (float)acc[n][rr] * sc + bp[rr];
            acc[n][rr] = __float_as_int(v);       // bit-cast in place
            s += v; q += v * v;
        }
    }
    s += __shfl_xor(s, 16); s += __shfl_xor(s, 32);
    q += __shfl_xor(q, 16); q += __shfl_xor(q, 32);
    if (lg == 0) {
        f32x2v sv; sv[0] = s; sv[1] = q;
        stats[wn * 16 + token] = sv;              // [wn][token], b64, conflict-free
    }
    __syncthreads();                              // BAR C (GEMM A4 reads also done)

    float st = 0.f, qt = 0.f;
#pragma unroll
    for (int w = 0; w < 4; w++) {
        f32x2v sv = stats[w * 16 + token];
        st += sv[0]; qt += sv[1];
    }
    float mean = st * (1.0f / 1024.0f);
    float rstd = rsqrtf(qt * (1.0f / 1024.0f) - mean * mean + 1e-5f);
    // no BAR D: T does not alias stats/sxl, and xs/A8 are dead

    // ---- phase 3b: LN2 apply + posemb, wave-private LDS transpose, nt stores ----
    // pe rows: cols<512 (wn 0,1) use pe2[half*16+token]; cols>=512 use pe2[gh]
    const float* perow = (wn < 2) ? (pe2 + (half * 16 + token) * 512)
                                  : (pe2 + gh * 512 - 512);
    int wbaseu = wave * 272;                      // 272 16B-units per wave region

#pragma unroll
    for (int p = 0; p < 4; p++) {
        // write pass: rows = token, slot = ni*4+lg (slot s <-> col offset 4s)
#pragma unroll
        for (int ni = 0; ni < 4; ni++) {
            int n = p * 4 + ni;
            int col = colbase + n * 16;
            f32x4v gg = *(const f32x4v*)(g2 + col);
            f32x4v bb = *(const f32x4v*)(b2 + col);
            f32x4v pv = *(const f32x4v*)(perow + col);
            f32x4v o;
#pragma unroll
            for (int rr = 0; rr < 4; rr++) {
                float v = __int_as_float(acc[n][rr]);
                o[rr] = (v - mean) * rstd * gg[rr] + bb[rr] + pv[rr];
            }
            T[wbaseu + l15 * 17 + ni * 4 + lg] = o;
        }
        // read-back: row = j*4+lg, slot = l15 -> 4 rows x 256 B contiguous stores
#pragma unroll
        for (int j = 0; j < 4; j++) {
            f32x4v v = T[wbaseu + (j * 4 + lg) * 17 + l15];
            int row = rowbase + j * 4 + lg;
            int col = wn * 256 + p * 64 + l15 * 4;
            __builtin_nontemporal_store(v, (f32x4v*)(out + (size_t)row * 1024 + col));
        }
    }
}

extern "C" void kernel_launch(void* const* d_in, const int* in_sizes, int n_in,
                              void* d_out, int out_size, void* d_ws, size_t ws_size,
                              hipStream_t stream) {
    const float* x     = (const float*)d_in[0];
    const float* ln1_g = (const float*)d_in[1];
    const float* ln1_b = (const float*)d_in[2];
    const float* W     = (const float*)d_in[3];
    const float* bproj = (const float*)d_in[4];
    const float* ln2_g = (const float*)d_in[5];
    const float* ln2_b = (const float*)d_in[6];
    float* out = (float*)d_out;

    // workspace layout
    char* ws = (char*)d_ws;
    float*       pe2   = (float*)ws;                           // 65,536 B
    signed char* Wq    = (signed char*)(ws + 65536u);          // 196,608 B
    float*       part  = (float*)(ws + 65536u + 196608u);      // 147 floats
    float*       swbuf = part + 160;

    prep1<<<211, 256, 0, stream>>>(W, part, pe2);
    wquant<<<768, 256, 0, stream>>>(W, part, swbuf, Wq);
    fused<<<4096, 256, 30720, stream>>>(x, ln1_g, ln1_b, Wq, swbuf, bproj,
                                        ln2_g, ln2_b, pe2, out);
}